// Round 11
// baseline (535.779 us; speedup 1.0000x reference)
//
#include <hip/hip_runtime.h>

#define NDIM 128

typedef __attribute__((ext_vector_type(8))) short s16x8;
typedef __attribute__((ext_vector_type(4))) float f32x4;

// fp32 -> bf16 (RNE) and back, bit-level (no header type friction)
__device__ __forceinline__ unsigned short f2bf(float f) {
    unsigned u = __float_as_uint(f);
    u += 0x7FFFu + ((u >> 16) & 1u);
    return (unsigned short)(u >> 16);
}
__device__ __forceinline__ float bf2f(unsigned short h) {
    return __uint_as_float((unsigned)h << 16);
}

// ---------------- edge-index normalization ----------------
__global__ __launch_bounds__(256) void detect_kernel(
    const int* __restrict__ raw, int* __restrict__ flag, int E) {
    __shared__ int any_nz;
    if (threadIdx.x == 0) any_nz = 0;
    __syncthreads();
    int local = 0;
    const int samples = (E < 4096) ? E : 4096;
#pragma unroll
    for (int j = 0; j < 16; ++j) {
        int i = threadIdx.x * 16 + j;
        if (i < samples) local |= raw[2 * i + 1];
    }
    if (local) atomicOr(&any_nz, 1);
    __syncthreads();
    if (threadIdx.x == 0) *flag = any_nz;   // nonzero -> int32 layout
}

__global__ void convert_kernel(const int* __restrict__ raw, const int* __restrict__ flag,
                               int* __restrict__ idx, int total) {
    int i = blockIdx.x * 256 + threadIdx.x;
    if (i >= total) return;
    idx[i] = (*flag == 0) ? raw[2 * i] : raw[i];
}

// ---------------- CSR build (counting sort by dst) ----------------
__global__ void hist_kernel(const int* __restrict__ idx, int* __restrict__ deg, int E) {
    int i = blockIdx.x * 256 + threadIdx.x;
    if (i < E) atomicAdd(&deg[idx[E + i]], 1);
}

__global__ __launch_bounds__(256) void deg_reduce_kernel(
    const int* __restrict__ deg, int* __restrict__ partials, int n) {
    const int base = blockIdx.x * 1024;
    const int tid = threadIdx.x;
    int s = 0;
#pragma unroll
    for (int j = 0; j < 4; ++j) {
        int i = base + tid * 4 + j;
        if (i < n) s += deg[i];
    }
#pragma unroll
    for (int off = 32; off; off >>= 1) s += __shfl_down(s, off);
    __shared__ int ws[4];
    if ((tid & 63) == 0) ws[tid >> 6] = s;
    __syncthreads();
    if (tid == 0) partials[blockIdx.x] = ws[0] + ws[1] + ws[2] + ws[3];
}

__global__ void scan_partials_kernel(int* __restrict__ partials, int nb,
                                     int* __restrict__ row_start, int n) {
    __shared__ int sh[1024];
    const int tid = threadIdx.x;
    int v = (tid < nb) ? partials[tid] : 0;
    sh[tid] = v;
    __syncthreads();
    for (int off = 1; off < 1024; off <<= 1) {
        int a = sh[tid];
        int b = (tid >= off) ? sh[tid - off] : 0;
        __syncthreads();
        sh[tid] = a + b;
        __syncthreads();
    }
    if (tid < nb) partials[tid] = (tid == 0) ? 0 : sh[tid - 1];
    if (tid == 0) row_start[n] = sh[1023];
}

__global__ __launch_bounds__(256) void deg_downsweep_kernel(
    const int* __restrict__ deg, const int* __restrict__ partials,
    int* __restrict__ row_start, int* __restrict__ cursor,
    float* __restrict__ inv_deg, int n) {
    const int base = blockIdx.x * 1024;
    const int tid = threadIdx.x;
    const int i0 = base + tid * 4;
    int d[4];
    int s = 0;
#pragma unroll
    for (int j = 0; j < 4; ++j) {
        int i = i0 + j;
        d[j] = (i < n) ? deg[i] : 0;
        s += d[j];
    }
    const int lane = tid & 63;
    int incl = s;
#pragma unroll
    for (int off = 1; off < 64; off <<= 1) {
        int t = __shfl_up(incl, off);
        if (lane >= off) incl += t;
    }
    __shared__ int wsum[4];
    if (lane == 63) wsum[tid >> 6] = incl;
    __syncthreads();
    int woff = 0;
    const int w = tid >> 6;
    for (int k = 0; k < w; ++k) woff += wsum[k];
    int excl = incl - s + woff + partials[blockIdx.x];
#pragma unroll
    for (int j = 0; j < 4; ++j) {
        int i = i0 + j;
        if (i < n) {
            row_start[i] = excl;
            cursor[i] = excl;
            inv_deg[i] = 1.0f / (float)max(d[j], 1);
            excl += d[j];
        }
    }
}

__global__ void scatter_kernel(const int* __restrict__ idx, int* __restrict__ cursor,
                               int* __restrict__ sorted_src, int E) {
    int i = blockIdx.x * 256 + threadIdx.x;
    if (i < E) {
        int d = idx[E + i];
        int p = atomicAdd(&cursor[d], 1);
        sorted_src[p] = idx[i];
    }
}

// ---------------- mean aggregation v3 (coalesced idx + shfl broadcast) -----
// R10 lesson: chunk-4 still paid a serialized ~300-cyc index load per chunk
// (all 32 lanes loading the same words). v3: ONE coalesced index load per 32
// edges (lane j holds sorted_src[beg+j]), broadcast via __shfl (in-register,
// no latency), gathers issued in predicated batches of 8 (clamped idx +
// mask-FMA tail) -> 8 outstanding vmem, idx stream off the critical path.
__global__ __launch_bounds__(256) void aggregate_kernel(
    const float* __restrict__ x, const int* __restrict__ row_start,
    const int* __restrict__ sorted_src, const float* __restrict__ inv_deg,
    float* __restrict__ aggr, int n) {
    int gid = blockIdx.x * 256 + threadIdx.x;
    int node = gid >> 5;
    if (node >= n) return;
    const int lane32 = threadIdx.x & 31;
    const int q = lane32 << 2;
    const int beg = row_start[node];
    const int end = row_start[node + 1];
    float4 acc = make_float4(0.f, 0.f, 0.f, 0.f);
    for (int base = beg; base < end; base += 32) {
        const int cnt = min(end - base, 32);
        const int my_src = (lane32 < cnt) ? sorted_src[base + lane32] : 0;
        for (int jb = 0; jb < cnt; jb += 8) {
            float4 v[8];
            float m[8];
#pragma unroll
            for (int t = 0; t < 8; ++t) {
                const int j = jb + t;
                const int js = (j < cnt) ? j : (cnt - 1);     // clamp: valid row
                const int s = __shfl(my_src, js, 32);
                v[t] = *(const float4*)(x + (size_t)s * NDIM + q);
                m[t] = (j < cnt) ? 1.f : 0.f;
            }
#pragma unroll
            for (int t = 0; t < 8; ++t) {
                acc.x = fmaf(m[t], v[t].x, acc.x);
                acc.y = fmaf(m[t], v[t].y, acc.y);
                acc.z = fmaf(m[t], v[t].z, acc.z);
                acc.w = fmaf(m[t], v[t].w, acc.w);
            }
        }
    }
    const float inv = inv_deg[node];
    acc.x *= inv; acc.y *= inv; acc.z *= inv; acc.w *= inv;
    *(float4*)(aggr + (size_t)node * NDIM + q) = acc;
}

// ---- pre-split + transpose W: Wl/Wr [5][128k][128n] fp32 ->
//      wth/wtl [mat(2)][5][n=128][k=128] bf16 (hi, lo) ----
__global__ __launch_bounds__(256) void presplit_kernel(
    const float* __restrict__ Wl, const float* __restrict__ Wr,
    short* __restrict__ wth, short* __restrict__ wtl, int total) {
    int idx = blockIdx.x * 256 + threadIdx.x;
    if (idx >= total) return;
    int k = idx & 127;
    int nn = (idx >> 7) & 127;
    int lm = idx >> 14;             // mat*5 + l, 0..9
    int mat = lm / 5;
    int l = lm % 5;
    const float* src = mat ? Wr : Wl;
    float v = src[(size_t)l * 16384 + (size_t)k * 128 + nn];   // transpose read
    unsigned short h = f2bf(v);
    unsigned short lo = f2bf(v - bf2f(h));
    wth[idx] = (short)h;
    wtl[idx] = (short)lo;
}

// ------- GEMM v7 (MFMA split-bf16): Y = Ag@Wl + X@Wr + b (+relu) -------
// fp32 via 3 bf16 products per matmul: Ah@Wh + Ah@Wl + Al@Wh (Al@Wl ~2^-18
// dropped). 256 thr / 4 waves, 64x128 tile, wave = 32 rows x 64 cols =
// 2x4 C-frags. K-chunks of 32. LDS 61.4 KB -> 2 blocks/CU.
// MFMA layouts [measured m89/m91/m120]: A: m=lane&15, k=quad*8+j;
// B: n=lane&15, k=quad*8+j; C/D: col=lane&15, row=quad*4+reg.
__global__ __launch_bounds__(256, 2) void gemm_kernel(
    const float* __restrict__ Ag, const float* __restrict__ X,
    const short* __restrict__ Wlh, const short* __restrict__ Wll,
    const short* __restrict__ Wrh, const short* __restrict__ Wrl,
    const float* __restrict__ bias, float* __restrict__ Y, int n, int do_relu) {
    __shared__ short sAgh[64][40], sAgl[64][40], sXh[64][40], sXl[64][40];
    __shared__ short sWlh[128][40], sWll[128][40], sWrh[128][40], sWrl[128][40];
    const int tid = threadIdx.x;
    const int lane = tid & 63;
    const int wave = tid >> 6;
    const int ln15 = lane & 15;
    const int quad = lane >> 4;
    const int row0 = blockIdx.x * 64;
    const int wr0 = (wave & 1) * 32;     // wave's row offset in tile
    const int wc0 = (wave >> 1) * 64;    // wave's col offset

    f32x4 acc[2][4];
#pragma unroll
    for (int i = 0; i < 2; ++i)
#pragma unroll
        for (int j = 0; j < 4; ++j) acc[i][j] = (f32x4)(0.f);

    // A staging assignment: thread -> (mat, row, k-half)
    const int sm = tid >> 7;            // 0=Ag, 1=X
    const int srow = (tid >> 1) & 63;
    const int sh = tid & 1;             // 16-float half of the 32-k chunk
    int arow = row0 + srow;
    if (arow >= n) arow = n - 1;
    const float* asrc = (sm ? X : Ag) + (size_t)arow * NDIM + sh * 16;
    short* dsthi = (sm ? &sXh[0][0] : &sAgh[0][0]) + srow * 40 + sh * 16;
    short* dstlo = (sm ? &sXl[0][0] : &sAgl[0][0]) + srow * 40 + sh * 16;

    // W staging assignment: 2 slots per thread, slot -> (wmat, wrow)
    const int wi0 = tid;                // slot 0
    const int wi1 = tid + 256;          // slot 1
    const int wm0 = wi0 >> 7, wrow0s = wi0 & 127;
    const int wm1 = wi1 >> 7, wrow1s = wi1 & 127;
    const short* wsrc0 = (wm0 == 0 ? Wlh : wm0 == 1 ? Wll : wm0 == 2 ? Wrh : Wrl) + wrow0s * 128;
    const short* wsrc1 = (wm1 == 0 ? Wlh : wm1 == 1 ? Wll : wm1 == 2 ? Wrh : Wrl) + wrow1s * 128;
    short* wdst0 = (wm0 == 0 ? &sWlh[0][0] : wm0 == 1 ? &sWll[0][0] : wm0 == 2 ? &sWrh[0][0] : &sWrl[0][0]) + wrow0s * 40;
    short* wdst1 = (wm1 == 0 ? &sWlh[0][0] : wm1 == 1 ? &sWll[0][0] : wm1 == 2 ? &sWrh[0][0] : &sWrl[0][0]) + wrow1s * 40;

    for (int k0 = 0; k0 < NDIM; k0 += 32) {
        // global reads for this chunk
        float4 f0 = *(const float4*)(asrc + k0);
        float4 f1 = *(const float4*)(asrc + k0 + 4);
        float4 f2 = *(const float4*)(asrc + k0 + 8);
        float4 f3 = *(const float4*)(asrc + k0 + 12);
        int4 wv0[2], wv1[2];
#pragma unroll
        for (int j = 0; j < 2; ++j) {
            wv0[j] = *(const int4*)(wsrc0 + k0 + j * 8);
            wv1[j] = *(const int4*)(wsrc1 + k0 + j * 8);
        }
        int4 wv0b[2], wv1b[2];
#pragma unroll
        for (int j = 0; j < 2; ++j) {
            wv0b[j] = *(const int4*)(wsrc0 + k0 + 16 + j * 8);
            wv1b[j] = *(const int4*)(wsrc1 + k0 + 16 + j * 8);
        }
        __syncthreads();
        // A split + LDS write
        {
            float vals[16] = {f0.x, f0.y, f0.z, f0.w, f1.x, f1.y, f1.z, f1.w,
                              f2.x, f2.y, f2.z, f2.w, f3.x, f3.y, f3.z, f3.w};
#pragma unroll
            for (int j = 0; j < 4; ++j) {
                unsigned short h[4], l[4];
#pragma unroll
                for (int m = 0; m < 4; ++m) {
                    float v = vals[j * 4 + m];
                    h[m] = f2bf(v);
                    l[m] = f2bf(v - bf2f(h[m]));
                }
                int2 wh = make_int2((int)(h[0] | ((unsigned)h[1] << 16)),
                                    (int)(h[2] | ((unsigned)h[3] << 16)));
                int2 wl = make_int2((int)(l[0] | ((unsigned)l[1] << 16)),
                                    (int)(l[2] | ((unsigned)l[3] << 16)));
                *(int2*)(dsthi + j * 4) = wh;
                *(int2*)(dstlo + j * 4) = wl;
            }
        }
        // W LDS write (copy, already bf16)
#pragma unroll
        for (int j = 0; j < 2; ++j) {
            ((int2*)(wdst0 + j * 8))[0] = make_int2(wv0[j].x, wv0[j].y);
            ((int2*)(wdst0 + j * 8))[1] = make_int2(wv0[j].z, wv0[j].w);
            ((int2*)(wdst1 + j * 8))[0] = make_int2(wv1[j].x, wv1[j].y);
            ((int2*)(wdst1 + j * 8))[1] = make_int2(wv1[j].z, wv1[j].w);
            ((int2*)(wdst0 + 16 + j * 8))[0] = make_int2(wv0b[j].x, wv0b[j].y);
            ((int2*)(wdst0 + 16 + j * 8))[1] = make_int2(wv0b[j].z, wv0b[j].w);
            ((int2*)(wdst1 + 16 + j * 8))[0] = make_int2(wv1b[j].x, wv1b[j].y);
            ((int2*)(wdst1 + 16 + j * 8))[1] = make_int2(wv1b[j].z, wv1b[j].w);
        }
        __syncthreads();

        // A fragments for this wave's 2 row-tiles
        s16x8 fAgh[2], fAgl[2], fXh[2], fXl[2];
#pragma unroll
        for (int rt = 0; rt < 2; ++rt) {
            const int r = wr0 + rt * 16 + ln15;
            const short* p;
            p = &sAgh[r][quad * 8];
            ((int2*)&fAgh[rt])[0] = *(const int2*)p; ((int2*)&fAgh[rt])[1] = *(const int2*)(p + 4);
            p = &sAgl[r][quad * 8];
            ((int2*)&fAgl[rt])[0] = *(const int2*)p; ((int2*)&fAgl[rt])[1] = *(const int2*)(p + 4);
            p = &sXh[r][quad * 8];
            ((int2*)&fXh[rt])[0] = *(const int2*)p; ((int2*)&fXh[rt])[1] = *(const int2*)(p + 4);
            p = &sXl[r][quad * 8];
            ((int2*)&fXl[rt])[0] = *(const int2*)p; ((int2*)&fXl[rt])[1] = *(const int2*)(p + 4);
        }
#pragma unroll
        for (int ct = 0; ct < 4; ++ct) {
            const int c = wc0 + ct * 16 + ln15;
            s16x8 blh, bll, brh, brl;
            const short* p;
            p = &sWlh[c][quad * 8];
            ((int2*)&blh)[0] = *(const int2*)p; ((int2*)&blh)[1] = *(const int2*)(p + 4);
            p = &sWll[c][quad * 8];
            ((int2*)&bll)[0] = *(const int2*)p; ((int2*)&bll)[1] = *(const int2*)(p + 4);
            p = &sWrh[c][quad * 8];
            ((int2*)&brh)[0] = *(const int2*)p; ((int2*)&brh)[1] = *(const int2*)(p + 4);
            p = &sWrl[c][quad * 8];
            ((int2*)&brl)[0] = *(const int2*)p; ((int2*)&brl)[1] = *(const int2*)(p + 4);
#pragma unroll
            for (int rt = 0; rt < 2; ++rt) {
                acc[rt][ct] = __builtin_amdgcn_mfma_f32_16x16x32_bf16(fAgh[rt], blh, acc[rt][ct], 0, 0, 0);
                acc[rt][ct] = __builtin_amdgcn_mfma_f32_16x16x32_bf16(fAgh[rt], bll, acc[rt][ct], 0, 0, 0);
                acc[rt][ct] = __builtin_amdgcn_mfma_f32_16x16x32_bf16(fAgl[rt], blh, acc[rt][ct], 0, 0, 0);
                acc[rt][ct] = __builtin_amdgcn_mfma_f32_16x16x32_bf16(fXh[rt], brh, acc[rt][ct], 0, 0, 0);
                acc[rt][ct] = __builtin_amdgcn_mfma_f32_16x16x32_bf16(fXh[rt], brl, acc[rt][ct], 0, 0, 0);
                acc[rt][ct] = __builtin_amdgcn_mfma_f32_16x16x32_bf16(fXl[rt], brh, acc[rt][ct], 0, 0, 0);
            }
        }
    }

    // epilogue: C/D layout col=lane&15, row=quad*4+reg [m89]
#pragma unroll
    for (int rt = 0; rt < 2; ++rt) {
#pragma unroll
        for (int ct = 0; ct < 4; ++ct) {
            const int col = wc0 + ct * 16 + ln15;
            const float bv = bias[col];
#pragma unroll
            for (int r = 0; r < 4; ++r) {
                const int grow = row0 + wr0 + rt * 16 + quad * 4 + r;
                if (grow < n) {
                    float v = acc[rt][ct][r] + bv;
                    if (do_relu) v = fmaxf(v, 0.f);
                    Y[(size_t)grow * NDIM + col] = v;
                }
            }
        }
    }
}

// ---------------- host launcher ----------------
extern "C" void kernel_launch(void* const* d_in, const int* in_sizes, int n_in,
                              void* d_out, int out_size, void* d_ws, size_t ws_size,
                              hipStream_t stream) {
    const float* x0   = (const float*)d_in[0];
    const int*   eraw = (const int*)d_in[1];
    const float* Wl   = (const float*)d_in[2];
    const float* bl   = (const float*)d_in[3];
    const float* Wr   = (const float*)d_in[4];
    float* out = (float*)d_out;

    const int N = in_sizes[0] / NDIM;   // 50000
    const int E = in_sizes[1] / 2;      // 600000

    auto align_up = [](size_t v) { return (v + 255) & ~(size_t)255; };
    char* p = (char*)d_ws;
    int* idx = (int*)p;                 p += align_up((size_t)2 * E * 4);
    int* deg = (int*)p;                 p += align_up((size_t)(N + 1) * 4);
    int* flag = deg + N;
    int* row_start = (int*)p;           p += align_up((size_t)(N + 1) * 4);
    int* cursor = (int*)p;              p += align_up((size_t)N * 4);
    int* ssrc = (int*)p;                p += align_up((size_t)E * 4);
    float* invd = (float*)p;            p += align_up((size_t)N * 4);
    int* partials = (int*)p;            p += align_up((size_t)1024 * 4);
    short* wth = (short*)p;             p += align_up((size_t)163840 * 2);
    short* wtl = (short*)p;             p += align_up((size_t)163840 * 2);
    float* buf0 = (float*)p;            p += align_up((size_t)N * NDIM * 4);
    float* buf1 = (float*)p;            p += align_up((size_t)N * NDIM * 4);

    const int nb = (N + 1023) / 1024;

    hipMemsetAsync(deg, 0, (size_t)N * 4, stream);
    detect_kernel<<<1, 256, 0, stream>>>(eraw, flag, E);
    convert_kernel<<<(2 * E + 255) / 256, 256, 0, stream>>>(eraw, flag, idx, 2 * E);
    hist_kernel<<<(E + 255) / 256, 256, 0, stream>>>(idx, deg, E);
    deg_reduce_kernel<<<nb, 256, 0, stream>>>(deg, partials, N);
    scan_partials_kernel<<<1, 1024, 0, stream>>>(partials, nb, row_start, N);
    deg_downsweep_kernel<<<nb, 256, 0, stream>>>(deg, partials, row_start, cursor, invd, N);
    scatter_kernel<<<(E + 255) / 256, 256, 0, stream>>>(idx, cursor, ssrc, E);
    presplit_kernel<<<640, 256, 0, stream>>>(Wl, Wr, wth, wtl, 163840);

    // Full-width 64-row-band gemm: all reads precede epilogue stores ->
    // in-place (Y == Ag) is safe (v4-verified launcher pattern).
    const float* xin = x0;
    for (int l = 0; l < 5; ++l) {
        float* ab = (l & 1) ? buf1 : buf0;
        aggregate_kernel<<<(N * 32 + 255) / 256, 256, 0, stream>>>(
            xin, row_start, ssrc, invd, ab, N);
        float* yo = (l == 4) ? out : ab;
        const short* wlh = wth + (size_t)l * 16384;
        const short* wll = wtl + (size_t)l * 16384;
        const short* wrh = wth + (size_t)(5 + l) * 16384;
        const short* wrl = wtl + (size_t)(5 + l) * 16384;
        gemm_kernel<<<(N + 63) / 64, 256, 0, stream>>>(
            ab, xin, wlh, wll, wrh, wrl,
            bl + (size_t)l * NDIM, yo, N, l < 4 ? 1 : 0);
        xin = yo;
    }
}

// Round 12
// 489.718 us; speedup vs baseline: 1.0941x; 1.0941x over previous
//
#include <hip/hip_runtime.h>

#define NDIM 128

typedef __attribute__((ext_vector_type(8))) short s16x8;
typedef __attribute__((ext_vector_type(4))) float f32x4;

// fp32 -> bf16 (RNE) and back, bit-level
__device__ __forceinline__ unsigned short f2bf(float f) {
    unsigned u = __float_as_uint(f);
    u += 0x7FFFu + ((u >> 16) & 1u);
    return (unsigned short)(u >> 16);
}
__device__ __forceinline__ float bf2f(unsigned short h) {
    return __uint_as_float((unsigned)h << 16);
}

// ---------------- edge-index normalization ----------------
__global__ __launch_bounds__(256) void detect_kernel(
    const int* __restrict__ raw, int* __restrict__ flag, int E) {
    __shared__ int any_nz;
    if (threadIdx.x == 0) any_nz = 0;
    __syncthreads();
    int local = 0;
    const int samples = (E < 4096) ? E : 4096;
#pragma unroll
    for (int j = 0; j < 16; ++j) {
        int i = threadIdx.x * 16 + j;
        if (i < samples) local |= raw[2 * i + 1];
    }
    if (local) atomicOr(&any_nz, 1);
    __syncthreads();
    if (threadIdx.x == 0) *flag = any_nz;   // nonzero -> int32 layout
}

// convert + fused degree histogram (R11: saves one 4.8 MB pass)
__global__ void convert_kernel(const int* __restrict__ raw, const int* __restrict__ flag,
                               int* __restrict__ idx, int* __restrict__ deg, int E) {
    int i = blockIdx.x * 256 + threadIdx.x;
    if (i >= 2 * E) return;
    int v = (*flag == 0) ? raw[2 * i] : raw[i];
    idx[i] = v;
    if (i >= E) atomicAdd(&deg[v], 1);   // dst words
}

__global__ __launch_bounds__(256) void deg_reduce_kernel(
    const int* __restrict__ deg, int* __restrict__ partials, int n) {
    const int base = blockIdx.x * 1024;
    const int tid = threadIdx.x;
    int s = 0;
#pragma unroll
    for (int j = 0; j < 4; ++j) {
        int i = base + tid * 4 + j;
        if (i < n) s += deg[i];
    }
#pragma unroll
    for (int off = 32; off; off >>= 1) s += __shfl_down(s, off);
    __shared__ int ws[4];
    if ((tid & 63) == 0) ws[tid >> 6] = s;
    __syncthreads();
    if (tid == 0) partials[blockIdx.x] = ws[0] + ws[1] + ws[2] + ws[3];
}

__global__ void scan_partials_kernel(int* __restrict__ partials, int nb,
                                     int* __restrict__ row_start, int n) {
    __shared__ int sh[1024];
    const int tid = threadIdx.x;
    int v = (tid < nb) ? partials[tid] : 0;
    sh[tid] = v;
    __syncthreads();
    for (int off = 1; off < 1024; off <<= 1) {
        int a = sh[tid];
        int b = (tid >= off) ? sh[tid - off] : 0;
        __syncthreads();
        sh[tid] = a + b;
        __syncthreads();
    }
    if (tid < nb) partials[tid] = (tid == 0) ? 0 : sh[tid - 1];
    if (tid == 0) row_start[n] = sh[1023];
}

__global__ __launch_bounds__(256) void deg_downsweep_kernel(
    const int* __restrict__ deg, const int* __restrict__ partials,
    int* __restrict__ row_start, int* __restrict__ cursor,
    float* __restrict__ inv_deg, int n) {
    const int base = blockIdx.x * 1024;
    const int tid = threadIdx.x;
    const int i0 = base + tid * 4;
    int d[4];
    int s = 0;
#pragma unroll
    for (int j = 0; j < 4; ++j) {
        int i = i0 + j;
        d[j] = (i < n) ? deg[i] : 0;
        s += d[j];
    }
    const int lane = tid & 63;
    int incl = s;
#pragma unroll
    for (int off = 1; off < 64; off <<= 1) {
        int t = __shfl_up(incl, off);
        if (lane >= off) incl += t;
    }
    __shared__ int wsum[4];
    if (lane == 63) wsum[tid >> 6] = incl;
    __syncthreads();
    int woff = 0;
    const int w = tid >> 6;
    for (int k = 0; k < w; ++k) woff += wsum[k];
    int excl = incl - s + woff + partials[blockIdx.x];
#pragma unroll
    for (int j = 0; j < 4; ++j) {
        int i = i0 + j;
        if (i < n) {
            row_start[i] = excl;
            cursor[i] = excl;
            inv_deg[i] = 1.0f / (float)max(d[j], 1);
            excl += d[j];
        }
    }
}

__global__ void scatter_kernel(const int* __restrict__ idx, int* __restrict__ cursor,
                               int* __restrict__ sorted_src, int E) {
    int i = blockIdx.x * 256 + threadIdx.x;
    if (i < E) {
        int d = idx[E + i];
        int p = atomicAdd(&cursor[d], 1);
        sorted_src[p] = idx[i];
    }
}

// ---------------- mean aggregation v3 (coalesced idx + shfl broadcast) -----
// R11: at the beyond-L2 gather plateau (~3 TB/s); MLP no longer the binding
// constraint. Kept as-is.
__global__ __launch_bounds__(256) void aggregate_kernel(
    const float* __restrict__ x, const int* __restrict__ row_start,
    const int* __restrict__ sorted_src, const float* __restrict__ inv_deg,
    float* __restrict__ aggr, int n) {
    int gid = blockIdx.x * 256 + threadIdx.x;
    int node = gid >> 5;
    if (node >= n) return;
    const int lane32 = threadIdx.x & 31;
    const int q = lane32 << 2;
    const int beg = row_start[node];
    const int end = row_start[node + 1];
    float4 acc = make_float4(0.f, 0.f, 0.f, 0.f);
    for (int base = beg; base < end; base += 32) {
        const int cnt = min(end - base, 32);
        const int my_src = (lane32 < cnt) ? sorted_src[base + lane32] : 0;
        for (int jb = 0; jb < cnt; jb += 8) {
            float4 v[8];
            float m[8];
#pragma unroll
            for (int t = 0; t < 8; ++t) {
                const int j = jb + t;
                const int js = (j < cnt) ? j : (cnt - 1);
                const int s = __shfl(my_src, js, 32);
                v[t] = *(const float4*)(x + (size_t)s * NDIM + q);
                m[t] = (j < cnt) ? 1.f : 0.f;
            }
#pragma unroll
            for (int t = 0; t < 8; ++t) {
                acc.x = fmaf(m[t], v[t].x, acc.x);
                acc.y = fmaf(m[t], v[t].y, acc.y);
                acc.z = fmaf(m[t], v[t].z, acc.z);
                acc.w = fmaf(m[t], v[t].w, acc.w);
            }
        }
    }
    const float inv = inv_deg[node];
    acc.x *= inv; acc.y *= inv; acc.z *= inv; acc.w *= inv;
    *(float4*)(aggr + (size_t)node * NDIM + q) = acc;
}

// ---- presplit v2: W -> MFMA B-fragment order, split bf16 hi/lo ----
// wfrag[l][plane(4)][chunk(4)][ct(8)][lane(64)][j(8)], plane: 0=Wl-hi,
// 1=Wl-lo, 2=Wr-hi, 3=Wr-lo. Element (lane,j) of (ct,chunk):
// n = ct*16 + (lane&15), k = chunk*32 + (lane>>4)*8 + j  [B-frag, m89/m91].
__global__ __launch_bounds__(256) void presplit_kernel(
    const float* __restrict__ Wl, const float* __restrict__ Wr,
    short* __restrict__ wfrag, int total) {
    int idx = blockIdx.x * 256 + threadIdx.x;
    if (idx >= total) return;
    int j = idx & 7;
    int lane = (idx >> 3) & 63;
    int ct = (idx >> 9) & 7;
    int chunk = (idx >> 12) & 3;
    int plane = (idx >> 14) & 3;
    int l = idx >> 16;
    int nn = ct * 16 + (lane & 15);
    int k = chunk * 32 + (lane >> 4) * 8 + j;
    const float* src = (plane < 2) ? Wl : Wr;
    float v = src[(size_t)l * 16384 + (size_t)k * 128 + nn];
    unsigned short h = f2bf(v);
    wfrag[idx] = (plane & 1) ? (short)f2bf(v - bf2f(h)) : (short)h;
}

// ------- GEMM v8 (MFMA split-bf16, W direct from global frag layout) -------
// R11 analysis: v7 was occupancy-bound (61.4 KB LDS -> 2 blocks/CU, 8
// waves/CU). v8: W fragments pre-arranged in global (presplit v2) and read
// with coalesced L2-hot global_load_dwordx4 -> LDS holds only A (20.5 KB),
// __launch_bounds__(256,4) -> 4 blocks/CU, 16 waves/CU. A frag reads are
// single ds_read_b128 (16B-aligned rows, stride 80 B).
// Spill tripwire: WRITE_SIZE must stay ~25 MB.
__global__ __launch_bounds__(256, 4) void gemm_kernel(
    const float* __restrict__ Ag, const float* __restrict__ X,
    const short* __restrict__ wfrag,   // this layer's 65536-elem block
    const float* __restrict__ bias, float* __restrict__ Y, int n, int do_relu) {
    __shared__ __align__(16) short sAgh[64][40];
    __shared__ __align__(16) short sAgl[64][40];
    __shared__ __align__(16) short sXh[64][40];
    __shared__ __align__(16) short sXl[64][40];
    const int tid = threadIdx.x;
    const int lane = tid & 63;
    const int wave = tid >> 6;
    const int ln15 = lane & 15;
    const int quad = lane >> 4;
    const int row0 = blockIdx.x * 64;
    const int wr0 = (wave & 1) * 32;     // wave's row offset
    const int wc0 = (wave >> 1) * 64;    // wave's col offset
    const int ctbase = (wave >> 1) * 4;  // global col-tile base

    f32x4 acc[2][4];
#pragma unroll
    for (int i = 0; i < 2; ++i)
#pragma unroll
        for (int j = 0; j < 4; ++j) acc[i][j] = (f32x4)(0.f);

    // A staging: thread -> (mat, row, k-half)
    const int sm = tid >> 7;            // 0=Ag, 1=X
    const int srow = (tid >> 1) & 63;
    const int sh = tid & 1;
    int arow = row0 + srow;
    if (arow >= n) arow = n - 1;
    const float* asrc = (sm ? X : Ag) + (size_t)arow * NDIM + sh * 16;
    short* dsthi = (sm ? &sXh[0][0] : &sAgh[0][0]) + srow * 40 + sh * 16;
    short* dstlo = (sm ? &sXl[0][0] : &sAgl[0][0]) + srow * 40 + sh * 16;

    for (int chunk = 0; chunk < 4; ++chunk) {
        const int k0 = chunk * 32;
        float4 f0 = *(const float4*)(asrc + k0);
        float4 f1 = *(const float4*)(asrc + k0 + 4);
        float4 f2 = *(const float4*)(asrc + k0 + 8);
        float4 f3 = *(const float4*)(asrc + k0 + 12);
        __syncthreads();
        {
            float vals[16] = {f0.x, f0.y, f0.z, f0.w, f1.x, f1.y, f1.z, f1.w,
                              f2.x, f2.y, f2.z, f2.w, f3.x, f3.y, f3.z, f3.w};
#pragma unroll
            for (int j = 0; j < 4; ++j) {
                unsigned short h[4], l[4];
#pragma unroll
                for (int m = 0; m < 4; ++m) {
                    float v = vals[j * 4 + m];
                    h[m] = f2bf(v);
                    l[m] = f2bf(v - bf2f(h[m]));
                }
                *(int2*)(dsthi + j * 4) = make_int2(
                    (int)(h[0] | ((unsigned)h[1] << 16)), (int)(h[2] | ((unsigned)h[3] << 16)));
                *(int2*)(dstlo + j * 4) = make_int2(
                    (int)(l[0] | ((unsigned)l[1] << 16)), (int)(l[2] | ((unsigned)l[3] << 16)));
            }
        }
        __syncthreads();

        // A fragments: one ds_read_b128 each
        s16x8 fAgh[2], fAgl[2], fXh[2], fXl[2];
#pragma unroll
        for (int rt = 0; rt < 2; ++rt) {
            const int r = wr0 + rt * 16 + ln15;
            fAgh[rt] = *(const s16x8*)&sAgh[r][quad * 8];
            fAgl[rt] = *(const s16x8*)&sAgl[r][quad * 8];
            fXh[rt]  = *(const s16x8*)&sXh[r][quad * 8];
            fXl[rt]  = *(const s16x8*)&sXl[r][quad * 8];
        }
#pragma unroll
        for (int ct = 0; ct < 4; ++ct) {
            const short* wb = wfrag + (chunk << 12) + ((ctbase + ct) << 9) + (lane << 3);
            const s16x8 blh = *(const s16x8*)(wb);            // Wl-hi
            const s16x8 bll = *(const s16x8*)(wb + 16384);    // Wl-lo
            const s16x8 brh = *(const s16x8*)(wb + 32768);    // Wr-hi
            const s16x8 brl = *(const s16x8*)(wb + 49152);    // Wr-lo
#pragma unroll
            for (int rt = 0; rt < 2; ++rt) {
                acc[rt][ct] = __builtin_amdgcn_mfma_f32_16x16x32_bf16(fAgh[rt], blh, acc[rt][ct], 0, 0, 0);
                acc[rt][ct] = __builtin_amdgcn_mfma_f32_16x16x32_bf16(fAgh[rt], bll, acc[rt][ct], 0, 0, 0);
                acc[rt][ct] = __builtin_amdgcn_mfma_f32_16x16x32_bf16(fAgl[rt], blh, acc[rt][ct], 0, 0, 0);
                acc[rt][ct] = __builtin_amdgcn_mfma_f32_16x16x32_bf16(fXh[rt],  brh, acc[rt][ct], 0, 0, 0);
                acc[rt][ct] = __builtin_amdgcn_mfma_f32_16x16x32_bf16(fXh[rt],  brl, acc[rt][ct], 0, 0, 0);
                acc[rt][ct] = __builtin_amdgcn_mfma_f32_16x16x32_bf16(fXl[rt],  brh, acc[rt][ct], 0, 0, 0);
            }
        }
    }

    // epilogue: C/D layout col=lane&15, row=quad*4+reg [m89]
#pragma unroll
    for (int rt = 0; rt < 2; ++rt) {
#pragma unroll
        for (int ct = 0; ct < 4; ++ct) {
            const int col = wc0 + ct * 16 + ln15;
            const float bv = bias[col];
#pragma unroll
            for (int r = 0; r < 4; ++r) {
                const int grow = row0 + wr0 + rt * 16 + quad * 4 + r;
                if (grow < n) {
                    float v = acc[rt][ct][r] + bv;
                    if (do_relu) v = fmaxf(v, 0.f);
                    Y[(size_t)grow * NDIM + col] = v;
                }
            }
        }
    }
}

// ---------------- host launcher ----------------
extern "C" void kernel_launch(void* const* d_in, const int* in_sizes, int n_in,
                              void* d_out, int out_size, void* d_ws, size_t ws_size,
                              hipStream_t stream) {
    const float* x0   = (const float*)d_in[0];
    const int*   eraw = (const int*)d_in[1];
    const float* Wl   = (const float*)d_in[2];
    const float* bl   = (const float*)d_in[3];
    const float* Wr   = (const float*)d_in[4];
    float* out = (float*)d_out;

    const int N = in_sizes[0] / NDIM;   // 50000
    const int E = in_sizes[1] / 2;      // 600000

    auto align_up = [](size_t v) { return (v + 255) & ~(size_t)255; };
    char* p = (char*)d_ws;
    int* idx = (int*)p;                 p += align_up((size_t)2 * E * 4);
    int* deg = (int*)p;                 p += align_up((size_t)(N + 1) * 4);
    int* flag = deg + N;
    int* row_start = (int*)p;           p += align_up((size_t)(N + 1) * 4);
    int* cursor = (int*)p;              p += align_up((size_t)N * 4);
    int* ssrc = (int*)p;                p += align_up((size_t)E * 4);
    float* invd = (float*)p;            p += align_up((size_t)N * 4);
    int* partials = (int*)p;            p += align_up((size_t)1024 * 4);
    short* wfrag = (short*)p;           p += align_up((size_t)327680 * 2);
    float* buf0 = (float*)p;            p += align_up((size_t)N * NDIM * 4);
    float* buf1 = (float*)p;            p += align_up((size_t)N * NDIM * 4);

    const int nb = (N + 1023) / 1024;

    hipMemsetAsync(deg, 0, (size_t)N * 4, stream);
    detect_kernel<<<1, 256, 0, stream>>>(eraw, flag, E);
    convert_kernel<<<(2 * E + 255) / 256, 256, 0, stream>>>(eraw, flag, idx, deg, E);
    deg_reduce_kernel<<<nb, 256, 0, stream>>>(deg, partials, N);
    scan_partials_kernel<<<1, 1024, 0, stream>>>(partials, nb, row_start, N);
    deg_downsweep_kernel<<<nb, 256, 0, stream>>>(deg, partials, row_start, cursor, invd, N);
    scatter_kernel<<<(E + 255) / 256, 256, 0, stream>>>(idx, cursor, ssrc, E);
    presplit_kernel<<<1280, 256, 0, stream>>>(Wl, Wr, wfrag, 327680);

    // Full-width 64-row-band gemm: all reads precede epilogue stores ->
    // in-place (Y == Ag) is safe.
    const float* xin = x0;
    for (int l = 0; l < 5; ++l) {
        float* ab = (l & 1) ? buf1 : buf0;
        aggregate_kernel<<<(N * 32 + 255) / 256, 256, 0, stream>>>(
            xin, row_start, ssrc, invd, ab, N);
        float* yo = (l == 4) ? out : ab;
        gemm_kernel<<<(N + 63) / 64, 256, 0, stream>>>(
            ab, xin, wfrag + (size_t)l * 65536,
            bl + (size_t)l * NDIM, yo, N, l < 4 ? 1 : 0);
        xin = yo;
    }
}